// Round 2
// baseline (163.305 us; speedup 1.0000x reference)
//
#include <hip/hip_runtime.h>
#include <hip/hip_bf16.h>

#define BB 16
#define NQ 64
#define NK 512
#define HD 256   // H = QS = KS = VD = 256

// ---------------------------------------------------------------------------
// Projection GEMM: C[M,256] = A[M,256] @ W[256,256], fp32, epilogue scale.
// BM=BN=64, BK=32, 256 threads, 4x4 register micro-tile per thread.
// scale folds the tanh exp2 constant (2/ln2) into the projection.
// ---------------------------------------------------------------------------
__global__ __launch_bounds__(256) void proj_gemm(const float* __restrict__ A,
                                                 const float* __restrict__ W,
                                                 float* __restrict__ C,
                                                 float scale) {
    const int K = 256, N = 256;
    __shared__ float As[32][68];   // [k][m]
    __shared__ float Bs[32][64];   // [k][n]

    const int t  = threadIdx.x;
    const int tx = t & 15;
    const int ty = t >> 4;
    const int rowBase = blockIdx.x * 64;
    const int colBase = blockIdx.y * 64;

    float acc[4][4] = {};

    for (int k0 = 0; k0 < K; k0 += 32) {
        {
            int m  = t >> 3;
            int kk = (t & 7) << 2;
            #pragma unroll
            for (int p = 0; p < 2; ++p, m += 32) {
                float4 a = *(const float4*)&A[(size_t)(rowBase + m) * K + k0 + kk];
                As[kk + 0][m] = a.x;
                As[kk + 1][m] = a.y;
                As[kk + 2][m] = a.z;
                As[kk + 3][m] = a.w;
            }
        }
        {
            int kr = t >> 4;
            int c4 = (t & 15) << 2;
            #pragma unroll
            for (int p = 0; p < 2; ++p, kr += 16) {
                *(float4*)&Bs[kr][c4] =
                    *(const float4*)&W[(size_t)(k0 + kr) * N + colBase + c4];
            }
        }
        __syncthreads();

        #pragma unroll
        for (int k = 0; k < 32; ++k) {
            float4 a4 = *(const float4*)&As[k][ty * 4];
            float4 b4 = *(const float4*)&Bs[k][tx * 4];
            float av[4] = {a4.x, a4.y, a4.z, a4.w};
            float bv[4] = {b4.x, b4.y, b4.z, b4.w};
            #pragma unroll
            for (int i = 0; i < 4; ++i)
                #pragma unroll
                for (int j = 0; j < 4; ++j)
                    acc[i][j] = fmaf(av[i], bv[j], acc[i][j]);
        }
        __syncthreads();
    }

    #pragma unroll
    for (int i = 0; i < 4; ++i) {
        int r = rowBase + ty * 4 + i;
        float4 o;
        o.x = acc[i][0] * scale;
        o.y = acc[i][1] * scale;
        o.z = acc[i][2] * scale;
        o.w = acc[i][3] * scale;
        *(float4*)&C[(size_t)r * N + colBase + tx * 4] = o;
    }
}

// ---------------------------------------------------------------------------
// Fused scores + masked softmax + attn@V.  One block per (b, q): 1024 blocks,
// 256 threads = 4 waves.
// Phase 1: each lane owns (one of 16 keys) x (one of 4 h-chunks of 64),
// fully unrolled 16-step h loop -> 16 scores per wave-iteration with only
// 2 shuffles, no serial reduction chain.
// tanh(x) = 1 - 2*rcp(exp2(x*2/ln2)+1); the 2/ln2 is pre-folded into qp/kp.
// Masked keys (n >= vl) skipped: exp(-1e6 - max) == 0 exactly in fp32, so
// this matches the reference bit-for-bit in softmax terms.
// ---------------------------------------------------------------------------
__global__ __launch_bounds__(256) void attn_kernel(
    const float* __restrict__ qp,      // [B*NQ, H]  (pre-scaled; lives in d_out)
    const float* __restrict__ kp,      // [B*NK, H]  (pre-scaled; lives in d_ws)
    const float* __restrict__ values,  // [B, NK, VD]
    const int*   __restrict__ vlens,   // [B]
    const float* __restrict__ w_v,     // [H]
    float* __restrict__ out)           // [B, NQ, VD] (same rows as qp)
{
    __shared__ float q_s[HD];
    __shared__ float wv_s[HD];
    __shared__ float sc[NK];
    __shared__ float part[4][HD];
    __shared__ float red[16];

    const int b    = blockIdx.x >> 6;
    const int qi   = blockIdx.x & 63;
    const int t    = threadIdx.x;
    const int lane = t & 63;
    const int wave = t >> 6;
    const int vl   = vlens[b];
    const size_t row = (size_t)(b * NQ + qi);

    q_s[t]  = qp[row * HD + t];
    wv_s[t] = w_v[t];
    __syncthreads();

    // ---- phase 1: scores ----
    const float* kbase = kp + (size_t)b * NK * HD;
    const int nLocal = lane & 15;        // which of 16 keys in the group
    const int hc     = (lane >> 4) << 6; // h-chunk base: 0,64,128,192

    for (int nBase = wave * 16; nBase < vl; nBase += 64) {
        const int n = nBase + nLocal;
        float p = 0.f;
        if (n < vl) {
            const float* krow = kbase + (size_t)n * HD + hc;
            const float* qrow = q_s + hc;
            const float* wrow = wv_s + hc;
            #pragma unroll
            for (int j = 0; j < 16; ++j) {
                float4 k4 = *(const float4*)&krow[j * 4];
                float4 q4 = *(const float4*)&qrow[j * 4];
                float4 w4 = *(const float4*)&wrow[j * 4];
                float e0 = __builtin_amdgcn_exp2f(q4.x + k4.x);
                float e1 = __builtin_amdgcn_exp2f(q4.y + k4.y);
                float e2 = __builtin_amdgcn_exp2f(q4.z + k4.z);
                float e3 = __builtin_amdgcn_exp2f(q4.w + k4.w);
                float t0 = fmaf(-2.f, __builtin_amdgcn_rcpf(e0 + 1.f), 1.f);
                float t1 = fmaf(-2.f, __builtin_amdgcn_rcpf(e1 + 1.f), 1.f);
                float t2 = fmaf(-2.f, __builtin_amdgcn_rcpf(e2 + 1.f), 1.f);
                float t3 = fmaf(-2.f, __builtin_amdgcn_rcpf(e3 + 1.f), 1.f);
                p = fmaf(w4.x, t0, p);
                p = fmaf(w4.y, t1, p);
                p = fmaf(w4.z, t2, p);
                p = fmaf(w4.w, t3, p);
            }
        }
        // reduce the 4 h-chunk partials: lanes l, l+16, l+32, l+48
        p += __shfl_down(p, 32);
        p += __shfl_down(p, 16);
        if (lane < 16 && n < vl) sc[n] = p;
    }
    __syncthreads();

    // ---- phase 2: masked softmax over sc[0..vl) ----
    float m = -1e30f;
    for (int n = t; n < vl; n += 256) m = fmaxf(m, sc[n]);
    #pragma unroll
    for (int off = 32; off; off >>= 1) m = fmaxf(m, __shfl_xor(m, off));
    if (lane == 0) red[wave] = m;
    __syncthreads();
    m = fmaxf(fmaxf(red[0], red[1]), fmaxf(red[2], red[3]));

    float ssum = 0.f;
    const float LOG2E = 1.4426950408889634f;
    for (int n = t; n < vl; n += 256) {
        float p = __builtin_amdgcn_exp2f((sc[n] - m) * LOG2E);
        sc[n] = p;
        ssum += p;
    }
    #pragma unroll
    for (int off = 32; off; off >>= 1) ssum += __shfl_xor(ssum, off);
    if (lane == 0) red[8 + wave] = ssum;
    __syncthreads();
    ssum = (red[8] + red[9]) + (red[10] + red[11]);
    const float inv = __builtin_amdgcn_rcpf(ssum);

    // ---- phase 3: out[b,qi,:] = (p/sum) @ V[b] ----
    float4 acc = {0.f, 0.f, 0.f, 0.f};
    const float* vbase = values + (size_t)b * NK * HD;
    for (int n = wave; n < vl; n += 4) {
        float p = sc[n];
        float4 v4 = *(const float4*)&vbase[(size_t)n * HD + lane * 4];
        acc.x = fmaf(p, v4.x, acc.x);
        acc.y = fmaf(p, v4.y, acc.y);
        acc.z = fmaf(p, v4.z, acc.z);
        acc.w = fmaf(p, v4.w, acc.w);
    }
    *(float4*)&part[wave][lane * 4] = acc;
    __syncthreads();

    if (wave == 0) {
        float4 p0 = *(const float4*)&part[0][lane * 4];
        float4 p1 = *(const float4*)&part[1][lane * 4];
        float4 p2 = *(const float4*)&part[2][lane * 4];
        float4 p3 = *(const float4*)&part[3][lane * 4];
        float4 o;
        o.x = ((p0.x + p1.x) + (p2.x + p3.x)) * inv;
        o.y = ((p0.y + p1.y) + (p2.y + p3.y)) * inv;
        o.z = ((p0.z + p1.z) + (p2.z + p3.z)) * inv;
        o.w = ((p0.w + p1.w) + (p2.w + p3.w)) * inv;
        *(float4*)&out[row * HD + lane * 4] = o;
    }
}

extern "C" void kernel_launch(void* const* d_in, const int* in_sizes, int n_in,
                              void* d_out, int out_size, void* d_ws, size_t ws_size,
                              hipStream_t stream) {
    const float* queries = (const float*)d_in[0];  // [16,64,256]
    const float* keys    = (const float*)d_in[1];  // [16,512,256]
    const float* values  = (const float*)d_in[2];  // [16,512,256]
    const int*   vlens   = (const int*)d_in[3];    // [16]
    const float* W_q     = (const float*)d_in[4];  // [256,256]
    const float* W_k     = (const float*)d_in[5];  // [256,256]
    const float* w_v     = (const float*)d_in[6];  // [256]
    float* out = (float*)d_out;                    // [16,64,256] fp32

    // Scratch budget: kp needs 8 MB -> put it at d_ws offset 0.
    // qp (1 MB) lives in d_out: each attn block reads only its own qp row
    // and overwrites exactly that row at the end (safe, race-free).
    float* kp = (float*)d_ws;                      // 8192*256 floats (8 MB)
    float* qp = out;                               // 1024*256 floats (1 MB)

    const float SC = 2.885390081777927f;           // 2/ln(2): tanh-exp2 prescale

    proj_gemm<<<dim3(16, 4),  256, 0, stream>>>(queries, W_q, qp, SC);
    proj_gemm<<<dim3(128, 4), 256, 0, stream>>>(keys,    W_k, kp, SC);
    attn_kernel<<<dim3(BB * NQ), 256, 0, stream>>>(qp, kp, values, vlens, w_v, out);
}

// Round 3
// 152.389 us; speedup vs baseline: 1.0716x; 1.0716x over previous
//
#include <hip/hip_runtime.h>
#include <hip/hip_bf16.h>

#define BB 16
#define NQ 64
#define NK 512
#define HD 256   // H = QS = KS = VD = 256

// ---------------------------------------------------------------------------
// Projection GEMM: C[M,256] = A[M,256] @ W[256,256], fp32, epilogue scale.
// BM=BN=64, BK=32, 256 threads, 4x4 micro-tile, register double-buffering
// of the global->LDS staging. scale folds the tanh 2/ln2 constant in.
// ---------------------------------------------------------------------------
__global__ __launch_bounds__(256, 2) void proj_gemm(const float* __restrict__ A,
                                                    const float* __restrict__ W,
                                                    float* __restrict__ C,
                                                    float scale) {
    const int K = 256, N = 256;
    __shared__ float As[32][68];   // [k][m]
    __shared__ float Bs[32][64];   // [k][n]

    const int t  = threadIdx.x;
    const int tx = t & 15;
    const int ty = t >> 4;
    const int rowBase = blockIdx.x * 64;
    const int colBase = blockIdx.y * 64;

    const int mA  = t >> 3;          // 0..31
    const int kkA = (t & 7) << 2;    // 0,4,..,28
    const int krB = t >> 4;          // 0..15
    const int c4B = (t & 15) << 2;   // 0,4,..,60

    // prefetch tile 0 into registers
    float4 a0 = *(const float4*)&A[(size_t)(rowBase + mA)      * K + kkA];
    float4 a1 = *(const float4*)&A[(size_t)(rowBase + mA + 32) * K + kkA];
    float4 b0 = *(const float4*)&W[(size_t)(krB)      * N + colBase + c4B];
    float4 b1 = *(const float4*)&W[(size_t)(krB + 16) * N + colBase + c4B];

    float acc[4][4] = {};

    for (int k0 = 0; k0 < K; k0 += 32) {
        // regs -> LDS
        As[kkA + 0][mA] = a0.x; As[kkA + 1][mA] = a0.y;
        As[kkA + 2][mA] = a0.z; As[kkA + 3][mA] = a0.w;
        As[kkA + 0][mA + 32] = a1.x; As[kkA + 1][mA + 32] = a1.y;
        As[kkA + 2][mA + 32] = a1.z; As[kkA + 3][mA + 32] = a1.w;
        *(float4*)&Bs[krB][c4B]      = b0;
        *(float4*)&Bs[krB + 16][c4B] = b1;
        __syncthreads();

        // prefetch next tile while computing this one
        if (k0 + 32 < K) {
            a0 = *(const float4*)&A[(size_t)(rowBase + mA)      * K + k0 + 32 + kkA];
            a1 = *(const float4*)&A[(size_t)(rowBase + mA + 32) * K + k0 + 32 + kkA];
            b0 = *(const float4*)&W[(size_t)(k0 + 32 + krB)      * N + colBase + c4B];
            b1 = *(const float4*)&W[(size_t)(k0 + 32 + krB + 16) * N + colBase + c4B];
        }

        #pragma unroll
        for (int k = 0; k < 32; ++k) {
            float4 a4 = *(const float4*)&As[k][ty * 4];
            float4 b4 = *(const float4*)&Bs[k][tx * 4];
            float av[4] = {a4.x, a4.y, a4.z, a4.w};
            float bv[4] = {b4.x, b4.y, b4.z, b4.w};
            #pragma unroll
            for (int i = 0; i < 4; ++i)
                #pragma unroll
                for (int j = 0; j < 4; ++j)
                    acc[i][j] = fmaf(av[i], bv[j], acc[i][j]);
        }
        __syncthreads();
    }

    #pragma unroll
    for (int i = 0; i < 4; ++i) {
        int r = rowBase + ty * 4 + i;
        float4 o;
        o.x = acc[i][0] * scale;
        o.y = acc[i][1] * scale;
        o.z = acc[i][2] * scale;
        o.w = acc[i][3] * scale;
        *(float4*)&C[(size_t)r * N + colBase + tx * 4] = o;
    }
}

// ---------------------------------------------------------------------------
// Fused scores + masked softmax + attn@V.  One block per (b, query-PAIR):
// 512 blocks x 256 threads.  Two queries per block double the arithmetic
// intensity of both the k-row reads (phase 1) and the V-row reads (phase 3).
// Phase 1 lane layout: lane -> (key = lane>>2, h-chunk = lane&3); per j the
// wave reads 16 key rows x 64B contiguous = 16 fully-used cache lines.
// tanh(x) = 1 - 2*rcp(exp2(x*2/ln2)+1); 2/ln2 pre-folded into qp/kp.
// Masked keys skipped: exp(-1e6 - max) == 0 exactly in fp32.
// ---------------------------------------------------------------------------
__global__ __launch_bounds__(256, 2) void attn_kernel(
    const float* __restrict__ qp,      // [B*NQ, H]  (pre-scaled; lives in d_out)
    const float* __restrict__ kp,      // [B*NK, H]  (pre-scaled; lives in d_ws)
    const float* __restrict__ values,  // [B, NK, VD]
    const int*   __restrict__ vlens,   // [B]
    const float* __restrict__ w_v,     // [H]
    float* __restrict__ out)           // [B, NQ, VD] (same rows as qp)
{
    __shared__ float q_s[2][HD];
    __shared__ float wv_s[HD];
    __shared__ float sc[2][NK];
    __shared__ float part[4][2][HD];
    __shared__ float redm[4], reds[4], invs[2];

    const int b    = blockIdx.x >> 5;     // 16 batches x 32 query-pairs
    const int qpair= blockIdx.x & 31;
    const int qi0  = qpair * 2;
    const int t    = threadIdx.x;
    const int lane = t & 63;
    const int wave = t >> 6;
    const int vl   = vlens[b];
    const size_t row0 = (size_t)b * NQ + qi0;

    q_s[0][t] = qp[row0 * HD + t];
    q_s[1][t] = qp[(row0 + 1) * HD + t];
    wv_s[t]   = w_v[t];
    __syncthreads();

    // ---- phase 1: scores for both queries ----
    const float* kbase = kp + (size_t)b * NK * HD;
    const int nLoc = lane >> 2;          // 0..15: key within the wave's group
    const int ch   = lane & 3;           // h-chunk (16B), stride 64B over j

    for (int nBase = wave * 16; nBase < vl; nBase += 64) {
        const int n = nBase + nLoc;
        float p0 = 0.f, p1 = 0.f;
        if (n < vl) {
            const float* krow = kbase + (size_t)n * HD + ch * 4;
            #pragma unroll
            for (int j = 0; j < 16; ++j) {
                const int ho = ch * 4 + j * 16;
                float4 k4 = *(const float4*)&krow[j * 16];
                float4 w4 = *(const float4*)&wv_s[ho];
                float4 qa = *(const float4*)&q_s[0][ho];
                float4 qb = *(const float4*)&q_s[1][ho];

                float e0 = __builtin_amdgcn_exp2f(qa.x + k4.x);
                float e1 = __builtin_amdgcn_exp2f(qa.y + k4.y);
                float e2 = __builtin_amdgcn_exp2f(qa.z + k4.z);
                float e3 = __builtin_amdgcn_exp2f(qa.w + k4.w);
                float t0 = fmaf(-2.f, __builtin_amdgcn_rcpf(e0 + 1.f), 1.f);
                float t1 = fmaf(-2.f, __builtin_amdgcn_rcpf(e1 + 1.f), 1.f);
                float t2 = fmaf(-2.f, __builtin_amdgcn_rcpf(e2 + 1.f), 1.f);
                float t3 = fmaf(-2.f, __builtin_amdgcn_rcpf(e3 + 1.f), 1.f);
                p0 = fmaf(w4.x, t0, p0);
                p0 = fmaf(w4.y, t1, p0);
                p0 = fmaf(w4.z, t2, p0);
                p0 = fmaf(w4.w, t3, p0);

                float f0 = __builtin_amdgcn_exp2f(qb.x + k4.x);
                float f1 = __builtin_amdgcn_exp2f(qb.y + k4.y);
                float f2 = __builtin_amdgcn_exp2f(qb.z + k4.z);
                float f3 = __builtin_amdgcn_exp2f(qb.w + k4.w);
                float u0 = fmaf(-2.f, __builtin_amdgcn_rcpf(f0 + 1.f), 1.f);
                float u1 = fmaf(-2.f, __builtin_amdgcn_rcpf(f1 + 1.f), 1.f);
                float u2 = fmaf(-2.f, __builtin_amdgcn_rcpf(f2 + 1.f), 1.f);
                float u3 = fmaf(-2.f, __builtin_amdgcn_rcpf(f3 + 1.f), 1.f);
                p1 = fmaf(w4.x, u0, p1);
                p1 = fmaf(w4.y, u1, p1);
                p1 = fmaf(w4.z, u2, p1);
                p1 = fmaf(w4.w, u3, p1);
            }
        }
        // reduce 4 h-chunks: lanes 4n, 4n+1, 4n+2, 4n+3
        p0 += __shfl_down(p0, 2); p0 += __shfl_down(p0, 1);
        p1 += __shfl_down(p1, 2); p1 += __shfl_down(p1, 1);
        if (ch == 0 && n < vl) { sc[0][n] = p0; sc[1][n] = p1; }
    }
    __syncthreads();

    // ---- phase 2: masked softmax, waves {0,1}->q0, {2,3}->q1 ----
    {
        const int qq  = wave >> 1;
        const int sub = wave & 1;
        float m = -1e30f;
        for (int n = sub * 64 + lane; n < vl; n += 128) m = fmaxf(m, sc[qq][n]);
        #pragma unroll
        for (int off = 32; off; off >>= 1) m = fmaxf(m, __shfl_xor(m, off));
        if (lane == 0) redm[wave] = m;
        __syncthreads();
        m = fmaxf(redm[qq * 2], redm[qq * 2 + 1]);

        float ssum = 0.f;
        const float L2E = 1.4426950408889634f;
        for (int n = sub * 64 + lane; n < vl; n += 128) {
            float p = __builtin_amdgcn_exp2f((sc[qq][n] - m) * L2E);
            sc[qq][n] = p;            // same-thread RMW
            ssum += p;
        }
        #pragma unroll
        for (int off = 32; off; off >>= 1) ssum += __shfl_xor(ssum, off);
        if (lane == 0) reds[wave] = ssum;
        __syncthreads();
        if (t == 0)  invs[0] = __builtin_amdgcn_rcpf(reds[0] + reds[1]);
        if (t == 64) invs[1] = __builtin_amdgcn_rcpf(reds[2] + reds[3]);
    }
    __syncthreads();

    // ---- phase 3: both outputs; 4 V-rows in flight per wave ----
    float4 acc0 = {0.f, 0.f, 0.f, 0.f};
    float4 acc1 = {0.f, 0.f, 0.f, 0.f};
    const float* vbase = values + (size_t)b * NK * HD;
    for (int nb = wave * 4; nb < vl; nb += 16) {
        #pragma unroll
        for (int u = 0; u < 4; ++u) {
            const int n = nb + u;
            if (n < vl) {
                float pa = sc[0][n];
                float pb = sc[1][n];
                float4 v4 = *(const float4*)&vbase[(size_t)n * HD + lane * 4];
                acc0.x = fmaf(pa, v4.x, acc0.x);
                acc0.y = fmaf(pa, v4.y, acc0.y);
                acc0.z = fmaf(pa, v4.z, acc0.z);
                acc0.w = fmaf(pa, v4.w, acc0.w);
                acc1.x = fmaf(pb, v4.x, acc1.x);
                acc1.y = fmaf(pb, v4.y, acc1.y);
                acc1.z = fmaf(pb, v4.z, acc1.z);
                acc1.w = fmaf(pb, v4.w, acc1.w);
            }
        }
    }
    *(float4*)&part[wave][0][lane * 4] = acc0;
    *(float4*)&part[wave][1][lane * 4] = acc1;
    __syncthreads();

    if (wave < 2) {
        float4 p0 = *(const float4*)&part[0][wave][lane * 4];
        float4 p1 = *(const float4*)&part[1][wave][lane * 4];
        float4 p2 = *(const float4*)&part[2][wave][lane * 4];
        float4 p3 = *(const float4*)&part[3][wave][lane * 4];
        const float inv = invs[wave];
        float4 o;
        o.x = ((p0.x + p1.x) + (p2.x + p3.x)) * inv;
        o.y = ((p0.y + p1.y) + (p2.y + p3.y)) * inv;
        o.z = ((p0.z + p1.z) + (p2.z + p3.z)) * inv;
        o.w = ((p0.w + p1.w) + (p2.w + p3.w)) * inv;
        *(float4*)&out[(row0 + wave) * HD + lane * 4] = o;
    }
}

extern "C" void kernel_launch(void* const* d_in, const int* in_sizes, int n_in,
                              void* d_out, int out_size, void* d_ws, size_t ws_size,
                              hipStream_t stream) {
    const float* queries = (const float*)d_in[0];  // [16,64,256]
    const float* keys    = (const float*)d_in[1];  // [16,512,256]
    const float* values  = (const float*)d_in[2];  // [16,512,256]
    const int*   vlens   = (const int*)d_in[3];    // [16]
    const float* W_q     = (const float*)d_in[4];  // [256,256]
    const float* W_k     = (const float*)d_in[5];  // [256,256]
    const float* w_v     = (const float*)d_in[6];  // [256]
    float* out = (float*)d_out;                    // [16,64,256] fp32

    // kp (8 MB) at d_ws offset 0; qp (1 MB) lives in d_out — each attn block
    // reads only its own 2 qp rows and overwrites exactly those rows at the
    // end (race-free).
    float* kp = (float*)d_ws;
    float* qp = out;

    const float SC = 2.885390081777927f;           // 2/ln(2): tanh-exp2 prescale

    proj_gemm<<<dim3(16, 4),  256, 0, stream>>>(queries, W_q, qp, SC);
    proj_gemm<<<dim3(128, 4), 256, 0, stream>>>(keys,    W_k, kp, SC);
    attn_kernel<<<dim3(BB * 32), 256, 0, stream>>>(qp, kp, values, vlens, w_v, out);
}

// Round 4
// 122.572 us; speedup vs baseline: 1.3323x; 1.2433x over previous
//
#include <hip/hip_runtime.h>
#include <hip/hip_bf16.h>

#define BB 16
#define NQ 64
#define NK 512
#define HD 256   // H = QS = KS = VD = 256

typedef __attribute__((ext_vector_type(8))) short short8;
typedef __attribute__((ext_vector_type(4))) float f32x4;

// fp32 -> bf16 round-to-nearest-even, bit-level (no lib types needed)
__device__ inline ushort bf16_rne(float v) {
    unsigned u = __float_as_uint(v);
    return (ushort)((u + 0x7FFFu + ((u >> 16) & 1u)) >> 16);
}
__device__ inline float bf16_to_f(ushort h) {
    return __uint_as_float(((unsigned)h) << 16);
}

// ---------------------------------------------------------------------------
// Merged projection GEMM on matrix cores, split-bf16 (hi/lo) for ~fp32 acc:
//   C = A @ W, A fp32 [M,256], W fp32 [256,256], C fp32, epilogue scale.
//   C ~= Ah*Wh + Al*Wh + Ah*Wl   (lo*lo dropped, ~2^-16 relative)
// Block tile 128x64, 4 waves (each 32x64 = 2x4 subtiles of 16x16), BK=64.
// blockIdx.x < 8 -> q-proj rows; else k-proj rows.  Grid (72, 4) = 288 blocks.
// MFMA 16x16x32 bf16 layouts (verified on gfx950):
//   A-frag: A[m=lane&15][k=quad*8+j]   (8 contiguous k -> ds_read_b128)
//   B-frag: B[k=quad*8+j][n=lane&15]   -> store W transposed [n][k] in LDS
//   C/D   : col=lane&15, row=quad*4+reg
// LDS rows padded 64->72 ushorts: unpadded 128B row stride = 16-way bank
// conflict on frag reads; 144B stride -> 2-way (free), keeps 16B alignment.
// ---------------------------------------------------------------------------
__global__ __launch_bounds__(256, 2) void proj_mfma(
    const float* __restrict__ queries, const float* __restrict__ keys,
    const float* __restrict__ W_q, const float* __restrict__ W_k,
    float* __restrict__ qp, float* __restrict__ kp, float scale)
{
    __shared__ ushort AsH[128][72];
    __shared__ ushort AsL[128][72];
    __shared__ ushort WtH[64][72];
    __shared__ ushort WtL[64][72];

    const float* A; const float* W; float* C; int rows0;
    const int rb = blockIdx.x;
    if (rb < 8) { A = queries; W = W_q; C = qp; rows0 = rb * 128; }
    else        { A = keys;    W = W_k; C = kp; rows0 = (rb - 8) * 128; }
    const int cols0 = blockIdx.y * 64;

    const int t    = threadIdx.x;
    const int lane = t & 63;
    const int wave = t >> 6;
    const int quad = lane >> 4;
    const int l15  = lane & 15;

    f32x4 acc[2][4];
    #pragma unroll
    for (int i = 0; i < 2; ++i)
        #pragma unroll
        for (int j = 0; j < 4; ++j)
            acc[i][j] = (f32x4){0.f, 0.f, 0.f, 0.f};

    for (int k0 = 0; k0 < 256; k0 += 64) {
        // ---- batched global loads (A: 8 f4/thread, W: 4 f4/thread) ----
        float4 av[8];
        #pragma unroll
        for (int i = 0; i < 8; ++i) {
            int idx = i * 256 + t;
            int row = idx >> 4, kf = (idx & 15) * 4;
            av[i] = *(const float4*)&A[(size_t)(rows0 + row) * 256 + k0 + kf];
        }
        float4 wv[4];
        #pragma unroll
        for (int i = 0; i < 4; ++i) {
            int idx = i * 256 + t;
            int krow = idx >> 4, nf = (idx & 15) * 4;
            wv[i] = *(const float4*)&W[(size_t)(k0 + krow) * 256 + cols0 + nf];
        }
        __syncthreads();   // previous compute done before overwriting LDS

        // ---- split to hi/lo bf16, write LDS ----
        #pragma unroll
        for (int i = 0; i < 8; ++i) {
            int idx = i * 256 + t;
            int row = idx >> 4, kf = (idx & 15) * 4;
            float fv[4] = {av[i].x, av[i].y, av[i].z, av[i].w};
            ushort hh[4], ll[4];
            #pragma unroll
            for (int c = 0; c < 4; ++c) {
                hh[c] = bf16_rne(fv[c]);
                ll[c] = bf16_rne(fv[c] - bf16_to_f(hh[c]));
            }
            *(ushort4*)&AsH[row][kf] = make_ushort4(hh[0], hh[1], hh[2], hh[3]);
            *(ushort4*)&AsL[row][kf] = make_ushort4(ll[0], ll[1], ll[2], ll[3]);
        }
        #pragma unroll
        for (int i = 0; i < 4; ++i) {
            int idx = i * 256 + t;
            int krow = idx >> 4, nf = (idx & 15) * 4;
            float fv[4] = {wv[i].x, wv[i].y, wv[i].z, wv[i].w};
            #pragma unroll
            for (int c = 0; c < 4; ++c) {
                ushort hh = bf16_rne(fv[c]);
                WtH[nf + c][krow] = hh;
                WtL[nf + c][krow] = bf16_rne(fv[c] - bf16_to_f(hh));
            }
        }
        __syncthreads();

        // ---- MFMA: 2 k32-steps, 2x4 subtiles, 3 products each ----
        #pragma unroll
        for (int ks = 0; ks < 64; ks += 32) {
            short8 aH[2], aL[2], bH[4], bL[4];
            #pragma unroll
            for (int ms = 0; ms < 2; ++ms) {
                int r = wave * 32 + ms * 16 + l15;
                aH[ms] = *(const short8*)&AsH[r][ks + quad * 8];
                aL[ms] = *(const short8*)&AsL[r][ks + quad * 8];
            }
            #pragma unroll
            for (int ns = 0; ns < 4; ++ns) {
                int n = ns * 16 + l15;
                bH[ns] = *(const short8*)&WtH[n][ks + quad * 8];
                bL[ns] = *(const short8*)&WtL[n][ks + quad * 8];
            }
            #pragma unroll
            for (int ms = 0; ms < 2; ++ms)
                #pragma unroll
                for (int ns = 0; ns < 4; ++ns) {
                    acc[ms][ns] = __builtin_amdgcn_mfma_f32_16x16x32_bf16(aH[ms], bH[ns], acc[ms][ns], 0, 0, 0);
                    acc[ms][ns] = __builtin_amdgcn_mfma_f32_16x16x32_bf16(aL[ms], bH[ns], acc[ms][ns], 0, 0, 0);
                    acc[ms][ns] = __builtin_amdgcn_mfma_f32_16x16x32_bf16(aH[ms], bL[ns], acc[ms][ns], 0, 0, 0);
                }
        }
    }

    // ---- epilogue: scale + store (C/D: col=lane&15, row=quad*4+reg) ----
    #pragma unroll
    for (int ms = 0; ms < 2; ++ms) {
        int rbase = rows0 + wave * 32 + ms * 16 + quad * 4;
        #pragma unroll
        for (int ns = 0; ns < 4; ++ns) {
            int col = cols0 + ns * 16 + l15;
            #pragma unroll
            for (int r = 0; r < 4; ++r)
                C[(size_t)(rbase + r) * 256 + col] = acc[ms][ns][r] * scale;
        }
    }
}

// ---------------------------------------------------------------------------
// Fused scores + masked softmax + attn@V.  One block per (b, query-pair),
// batch-swizzled (b = blk & 15) for CU load balance + per-XCD L2 locality.
// Phase 1: per lane, 16 k-row float4 loads batched into registers (MLP=16)
// before the transcendental loop.  score = Wsum - 2*sum_h w*rcp(exp2(xs)+1),
// xs pre-scaled by 2/ln2 in the projections.
// Masked keys skipped: exp(-1e6 - max) == 0 exactly in fp32.
// ---------------------------------------------------------------------------
__global__ __launch_bounds__(256, 2) void attn_kernel(
    const float* __restrict__ qp,      // [B*NQ, H]  (pre-scaled; lives in d_out)
    const float* __restrict__ kp,      // [B*NK, H]  (pre-scaled; lives in d_ws)
    const float* __restrict__ values,  // [B, NK, VD]
    const int*   __restrict__ vlens,   // [B]
    const float* __restrict__ w_v,     // [H]
    float* __restrict__ out)           // [B, NQ, VD] (same rows as qp)
{
    __shared__ float q_s[2][HD];
    __shared__ float wv_s[HD];
    __shared__ float sc[2][NK];
    __shared__ float part[4][2][HD];
    __shared__ float redm[4], reds[4], invs[2];

    const int b     = blockIdx.x & 15;    // swizzle: consecutive blocks -> different batches
    const int qpair = blockIdx.x >> 4;
    const int qi0   = qpair * 2;
    const int t     = threadIdx.x;
    const int lane  = t & 63;
    const int wave  = t >> 6;
    const int vl    = vlens[b];
    const size_t row0 = (size_t)b * NQ + qi0;

    q_s[0][t] = qp[row0 * HD + t];
    q_s[1][t] = qp[(row0 + 1) * HD + t];
    wv_s[t]   = w_v[t];
    __syncthreads();

    // Wsum = sum_h w_v[h]  (per-wave redundant reduce, no extra barrier)
    float Wsum;
    {
        float ws = wv_s[lane] + wv_s[lane + 64] + wv_s[lane + 128] + wv_s[lane + 192];
        #pragma unroll
        for (int off = 32; off; off >>= 1) ws += __shfl_xor(ws, off);
        Wsum = ws;
    }

    // ---- phase 1: scores for both queries ----
    const float* kbase = kp + (size_t)b * NK * HD;
    const int nLoc = lane >> 2;          // key within the wave's 16-key group
    const int ch   = lane & 3;           // 16B h-chunk, stride 64B over j

    for (int nBase = wave * 16; nBase < vl; nBase += 64) {
        const int n = nBase + nLoc;
        float p0 = 0.f, p1 = 0.f;
        if (n < vl) {
            const float* krow = kbase + (size_t)n * HD + ch * 4;
            float4 kk[16];
            #pragma unroll
            for (int j = 0; j < 16; ++j) kk[j] = *(const float4*)&krow[j * 16];
            #pragma unroll
            for (int j = 0; j < 16; ++j) {
                const int ho = ch * 4 + j * 16;
                float4 k4 = kk[j];
                float4 w4 = *(const float4*)&wv_s[ho];
                float4 qa = *(const float4*)&q_s[0][ho];
                float4 qb = *(const float4*)&q_s[1][ho];

                float r0 = __builtin_amdgcn_rcpf(__builtin_amdgcn_exp2f(qa.x + k4.x) + 1.f);
                float r1 = __builtin_amdgcn_rcpf(__builtin_amdgcn_exp2f(qa.y + k4.y) + 1.f);
                float r2 = __builtin_amdgcn_rcpf(__builtin_amdgcn_exp2f(qa.z + k4.z) + 1.f);
                float r3 = __builtin_amdgcn_rcpf(__builtin_amdgcn_exp2f(qa.w + k4.w) + 1.f);
                p0 = fmaf(w4.x, r0, p0);
                p0 = fmaf(w4.y, r1, p0);
                p0 = fmaf(w4.z, r2, p0);
                p0 = fmaf(w4.w, r3, p0);

                float s0 = __builtin_amdgcn_rcpf(__builtin_amdgcn_exp2f(qb.x + k4.x) + 1.f);
                float s1 = __builtin_amdgcn_rcpf(__builtin_amdgcn_exp2f(qb.y + k4.y) + 1.f);
                float s2 = __builtin_amdgcn_rcpf(__builtin_amdgcn_exp2f(qb.z + k4.z) + 1.f);
                float s3 = __builtin_amdgcn_rcpf(__builtin_amdgcn_exp2f(qb.w + k4.w) + 1.f);
                p1 = fmaf(w4.x, s0, p1);
                p1 = fmaf(w4.y, s1, p1);
                p1 = fmaf(w4.z, s2, p1);
                p1 = fmaf(w4.w, s3, p1);
            }
        }
        // reduce 4 h-chunk partials (lanes 4n..4n+3)
        p0 += __shfl_down(p0, 2); p0 += __shfl_down(p0, 1);
        p1 += __shfl_down(p1, 2); p1 += __shfl_down(p1, 1);
        if (ch == 0 && n < vl) {
            sc[0][n] = fmaf(-2.f, p0, Wsum);
            sc[1][n] = fmaf(-2.f, p1, Wsum);
        }
    }
    __syncthreads();

    // ---- phase 2: masked softmax, waves {0,1}->q0, {2,3}->q1 ----
    const int vla = (vl + 15) & ~15;     // 16-aligned (<= 512)
    {
        const int qq  = wave >> 1;
        const int sub = wave & 1;
        float m = -1e30f;
        for (int n = sub * 64 + lane; n < vl; n += 128) m = fmaxf(m, sc[qq][n]);
        #pragma unroll
        for (int off = 32; off; off >>= 1) m = fmaxf(m, __shfl_xor(m, off));
        if (lane == 0) redm[wave] = m;
        __syncthreads();
        m = fmaxf(redm[qq * 2], redm[qq * 2 + 1]);

        float ssum = 0.f;
        const float L2E = 1.4426950408889634f;
        for (int n = sub * 64 + lane; n < vl; n += 128) {
            float p = __builtin_amdgcn_exp2f((sc[qq][n] - m) * L2E);
            sc[qq][n] = p;            // same-thread RMW
            ssum += p;
        }
        #pragma unroll
        for (int off = 32; off; off >>= 1) ssum += __shfl_xor(ssum, off);
        if (lane == 0) reds[wave] = ssum;
        // zero-pad sc up to the 16-aligned edge so phase 3 runs guard-free
        if (vl + t < vla) { sc[0][vl + t] = 0.f; sc[1][vl + t] = 0.f; }
        __syncthreads();
        if (t == 0)  invs[0] = __builtin_amdgcn_rcpf(reds[0] + reds[1]);
        if (t == 64) invs[1] = __builtin_amdgcn_rcpf(reds[2] + reds[3]);
    }
    __syncthreads();

    // ---- phase 3: both outputs; batched V loads, no guards ----
    float4 acc0 = {0.f, 0.f, 0.f, 0.f};
    float4 acc1 = {0.f, 0.f, 0.f, 0.f};
    const float* vbase = values + (size_t)b * NK * HD;
    for (int nb = wave * 4; nb < vla; nb += 16) {
        float4 v[4]; float pa[4], pb[4];
        #pragma unroll
        for (int u = 0; u < 4; ++u) {
            v[u]  = *(const float4*)&vbase[(size_t)(nb + u) * HD + lane * 4];
            pa[u] = sc[0][nb + u];
            pb[u] = sc[1][nb + u];
        }
        #pragma unroll
        for (int u = 0; u < 4; ++u) {
            acc0.x = fmaf(pa[u], v[u].x, acc0.x);
            acc0.y = fmaf(pa[u], v[u].y, acc0.y);
            acc0.z = fmaf(pa[u], v[u].z, acc0.z);
            acc0.w = fmaf(pa[u], v[u].w, acc0.w);
            acc1.x = fmaf(pb[u], v[u].x, acc1.x);
            acc1.y = fmaf(pb[u], v[u].y, acc1.y);
            acc1.z = fmaf(pb[u], v[u].z, acc1.z);
            acc1.w = fmaf(pb[u], v[u].w, acc1.w);
        }
    }
    *(float4*)&part[wave][0][lane * 4] = acc0;
    *(float4*)&part[wave][1][lane * 4] = acc1;
    __syncthreads();

    if (wave < 2) {
        float4 p0 = *(const float4*)&part[0][wave][lane * 4];
        float4 p1 = *(const float4*)&part[1][wave][lane * 4];
        float4 p2 = *(const float4*)&part[2][wave][lane * 4];
        float4 p3 = *(const float4*)&part[3][wave][lane * 4];
        const float inv = invs[wave];
        float4 o;
        o.x = ((p0.x + p1.x) + (p2.x + p3.x)) * inv;
        o.y = ((p0.y + p1.y) + (p2.y + p3.y)) * inv;
        o.z = ((p0.z + p1.z) + (p2.z + p3.z)) * inv;
        o.w = ((p0.w + p1.w) + (p2.w + p3.w)) * inv;
        *(float4*)&out[(row0 + wave) * HD + lane * 4] = o;
    }
}

extern "C" void kernel_launch(void* const* d_in, const int* in_sizes, int n_in,
                              void* d_out, int out_size, void* d_ws, size_t ws_size,
                              hipStream_t stream) {
    const float* queries = (const float*)d_in[0];  // [16,64,256]
    const float* keys    = (const float*)d_in[1];  // [16,512,256]
    const float* values  = (const float*)d_in[2];  // [16,512,256]
    const int*   vlens   = (const int*)d_in[3];    // [16]
    const float* W_q     = (const float*)d_in[4];  // [256,256]
    const float* W_k     = (const float*)d_in[5];  // [256,256]
    const float* w_v     = (const float*)d_in[6];  // [256]
    float* out = (float*)d_out;                    // [16,64,256] fp32

    // kp (8 MB) at d_ws offset 0; qp (1 MB) lives in d_out — each attn block
    // reads only its own 2 qp rows and overwrites exactly those rows (race-free).
    float* kp = (float*)d_ws;
    float* qp = out;

    const float SC = 2.885390081777927f;           // 2/ln(2): tanh-exp2 prescale

    proj_mfma<<<dim3(72, 4), 256, 0, stream>>>(queries, keys, W_q, W_k, qp, kp, SC);
    attn_kernel<<<dim3(512), 256, 0, stream>>>(qp, kp, values, vlens, w_v, out);
}